// Round 1
// baseline (379.112 us; speedup 1.0000x reference)
//
#include <hip/hip_runtime.h>
#include <math.h>

#define FCLAMP 10000.0f
#define LQ 256
#define NCYC 1024
#define WDIM 8

__device__ __forceinline__ float safef(float x) {
    if (isnan(x)) return 0.0f;
    x = fminf(x, FCLAMP);
    x = fmaxf(x, -FCLAMP);
    return x;
}

__device__ __forceinline__ float wsum(float v) {
#pragma unroll
    for (int o = 32; o > 0; o >>= 1) v += __shfl_down(v, o, 64);
    return v;
}

__device__ __forceinline__ float wmax(float v) {
#pragma unroll
    for (int o = 32; o > 0; o >>= 1) v = fmaxf(v, __shfl_down(v, o, 64));
    return v;
}

// ---------------------------------------------------------------------------
// Kernel 1: one block per cycle (256 threads, one per dart).
// Does: orientation normalization, dart embed, cycle attention (3-neighbor),
// residual+LN, softmax pooling, per-cycle MLP -> cycle token, and the
// per-token QKV for the global attention stage.
// ---------------------------------------------------------------------------
__global__ __launch_bounds__(LQ) void k_cycle(
    const float* __restrict__ df,
    const float* __restrict__ de_w, const float* __restrict__ de_b,
    const float* __restrict__ ca_in_w, const float* __restrict__ ca_in_b,
    const float* __restrict__ ca_out_w, const float* __restrict__ ca_out_b,
    const float* __restrict__ cn_g, const float* __restrict__ cn_b,
    const float* __restrict__ cs_w, const float* __restrict__ cs_b,
    const float* __restrict__ cp_ln_g, const float* __restrict__ cp_ln_b,
    const float* __restrict__ cp_w1, const float* __restrict__ cp_b1,
    const float* __restrict__ cp_w2, const float* __restrict__ cp_b2,
    const float* __restrict__ ia_in_w, const float* __restrict__ ia_in_b,
    float* __restrict__ ws_cyc,   // [NCYC][8]
    float* __restrict__ ws_qkv)   // [NCYC][24]
{
    __shared__ float sdx[LQ], sdy[LQ];   // raw darts
    __shared__ float px[LQ], py[LQ];     // scan buffers
    __shared__ float sk[LQ][WDIM];       // k (later reused as pool scratch)
    __shared__ float sv[LQ][WDIM];       // v
    __shared__ float sred[4];
    __shared__ float sbc;

    const int tid  = threadIdx.x;
    const int nc   = blockIdx.x;
    const int lane = tid & 63;
    const int wid  = tid >> 6;

    const float* base = df + (size_t)nc * (LQ * 3);
    const float dx = base[tid * 3 + 0];
    const float dy = base[tid * 3 + 1];
    sdx[tid] = dx; sdy[tid] = dy;
    px[tid] = dx;  py[tid] = dy;
    __syncthreads();

    // Inclusive Hillis-Steele scan of darts (for vertex prefix sums).
    for (int off = 1; off < LQ; off <<= 1) {
        float ax = 0.f, ay = 0.f;
        if (tid >= off) { ax = px[tid - off]; ay = py[tid - off]; }
        __syncthreads();
        px[tid] += ax; py[tid] += ay;
        __syncthreads();
    }
    // Exclusive prefix = vertex position v_i; shoelace area = 0.5 * sum cross(v_i, d_i), i<L-1
    const float vx = (tid > 0) ? px[tid - 1] : 0.f;
    const float vy = (tid > 0) ? py[tid - 1] : 0.f;
    float c = (tid < LQ - 1) ? (vx * dy - vy * dx) : 0.f;
    float s = wsum(c);
    if (lane == 0) sred[wid] = s;
    __syncthreads();
    if (tid == 0) sbc = sred[0] + sred[1] + sred[2] + sred[3];
    __syncthreads();
    const bool flip = !(sbc >= 0.f);   // matches jnp.where(area >= 0, keep, flip)

    float xx, yy;
    if (flip) { xx = -sdx[LQ - 1 - tid]; yy = -sdy[LQ - 1 - tid]; }
    else      { xx =  sdx[tid];          yy =  sdy[tid]; }

    const float fx = safef(xx);
    const float fy = safef(yy);
    const float fn = safef(sqrtf(xx * xx + yy * yy));

    // emb = safe(relu(feats @ de_w.T + de_b))
    float emb[WDIM];
#pragma unroll
    for (int j = 0; j < WDIM; ++j) {
        float e = de_b[j] + fx * de_w[j * 3 + 0] + fy * de_w[j * 3 + 1] + fn * de_w[j * 3 + 2];
        emb[j] = safef(fmaxf(e, 0.f));
    }

    // qkv = emb @ ca_in_w.T + ca_in_b ; q in regs, k/v in LDS
    float q[WDIM];
#pragma unroll
    for (int o = 0; o < 24; ++o) {
        float val = ca_in_b[o];
#pragma unroll
        for (int k = 0; k < WDIM; ++k) val += emb[k] * ca_in_w[o * WDIM + k];
        if (o < 8)       q[o] = val;
        else if (o < 16) sk[tid][o - 8]  = val;
        else             sv[tid][o - 16] = val;
    }
    __syncthreads();

    // Cycle attention: mask allows only {i-1, i, i+1} (circular); exact 3-way softmax.
    const int ip  = (tid + LQ - 1) & (LQ - 1);
    const int inx = (tid + 1) & (LQ - 1);
    float attn8[WDIM];
#pragma unroll
    for (int h = 0; h < 2; ++h) {
        float s0 = 0.f, s1 = 0.f, s2 = 0.f;
#pragma unroll
        for (int d = 0; d < 4; ++d) {
            const float qv = q[h * 4 + d];
            s0 += qv * sk[ip][h * 4 + d];
            s1 += qv * sk[tid][h * 4 + d];
            s2 += qv * sk[inx][h * 4 + d];
        }
        s0 *= 0.5f; s1 *= 0.5f; s2 *= 0.5f;   // / sqrt(d=4)
        const float m  = fmaxf(s0, fmaxf(s1, s2));
        const float e0 = expf(s0 - m), e1 = expf(s1 - m), e2 = expf(s2 - m);
        const float inv = 1.f / (e0 + e1 + e2);
#pragma unroll
        for (int d = 0; d < 4; ++d)
            attn8[h * 4 + d] = (e0 * sv[ip][h * 4 + d] + e1 * sv[tid][h * 4 + d] +
                                e2 * sv[inx][h * 4 + d]) * inv;
    }

    // out proj + residual + safe + LN + safe
    float x8[WDIM];
#pragma unroll
    for (int j = 0; j < WDIM; ++j) {
        float ao = ca_out_b[j];
#pragma unroll
        for (int k = 0; k < WDIM; ++k) ao += attn8[k] * ca_out_w[j * WDIM + k];
        x8[j] = safef(emb[j] + ao);
    }
    float mu = 0.f;
#pragma unroll
    for (int j = 0; j < WDIM; ++j) mu += x8[j];
    mu *= (1.f / WDIM);
    float var = 0.f;
#pragma unroll
    for (int j = 0; j < WDIM; ++j) { const float d = x8[j] - mu; var += d * d; }
    var *= (1.f / WDIM);
    const float rs = rsqrtf(var + 1e-5f);
    float emb2[WDIM];
#pragma unroll
    for (int j = 0; j < WDIM; ++j)
        emb2[j] = safef((x8[j] - mu) * rs * cn_g[j] + cn_b[j]);

    // scoring logit + block softmax over the 256 darts
    float lg = cs_b[0];
#pragma unroll
    for (int j = 0; j < WDIM; ++j) lg += emb2[j] * cs_w[j];
    lg = safef(lg);

    float m1 = wmax(lg);
    if (lane == 0) sred[wid] = m1;
    __syncthreads();
    if (tid == 0) sbc = fmaxf(fmaxf(sred[0], sred[1]), fmaxf(sred[2], sred[3]));
    __syncthreads();
    const float M = sbc;
    const float e = expf(lg - M);
    float ps = wsum(e);
    __syncthreads();
    if (lane == 0) sred[wid] = ps;
    __syncthreads();
    if (tid == 0) sbc = sred[0] + sred[1] + sred[2] + sred[3];
    __syncthreads();
    const float wgt = e / sbc;

    // pooled[j] = sum_i wgt_i * emb2_i[j]  (LDS tree reduce; reuse sk)
#pragma unroll
    for (int j = 0; j < WDIM; ++j) sk[tid][j] = wgt * emb2[j];
    __syncthreads();
    for (int stride = 128; stride >= 1; stride >>= 1) {
        if (tid < stride) {
#pragma unroll
            for (int j = 0; j < WDIM; ++j) sk[tid][j] += sk[tid + stride][j];
        }
        __syncthreads();
    }

    if (tid == 0) {
        float p[WDIM];
#pragma unroll
        for (int j = 0; j < WDIM; ++j) p[j] = sk[0][j];
        // hpool = LN(pooled)
        float mu2 = 0.f;
#pragma unroll
        for (int j = 0; j < WDIM; ++j) mu2 += p[j];
        mu2 *= (1.f / WDIM);
        float var2 = 0.f;
#pragma unroll
        for (int j = 0; j < WDIM; ++j) { const float d = p[j] - mu2; var2 += d * d; }
        var2 *= (1.f / WDIM);
        const float rs2 = rsqrtf(var2 + 1e-5f);
        float hh[WDIM];
#pragma unroll
        for (int j = 0; j < WDIM; ++j) hh[j] = (p[j] - mu2) * rs2 * cp_ln_g[j] + cp_ln_b[j];
        // cyc = safe(relu(hh @ w1.T + b1) @ w2.T + b2)
        float r[WDIM];
#pragma unroll
        for (int j = 0; j < WDIM; ++j) {
            float a = cp_b1[j];
#pragma unroll
            for (int k = 0; k < WDIM; ++k) a += hh[k] * cp_w1[j * WDIM + k];
            r[j] = fmaxf(a, 0.f);
        }
        float cy[WDIM];
#pragma unroll
        for (int j = 0; j < WDIM; ++j) {
            float a = cp_b2[j];
#pragma unroll
            for (int k = 0; k < WDIM; ++k) a += r[k] * cp_w2[j * WDIM + k];
            cy[j] = safef(a);
            ws_cyc[nc * WDIM + j] = cy[j];
        }
        // Global-attention QKV for this token (per-token op: fold in here)
#pragma unroll
        for (int o = 0; o < 24; ++o) {
            float a = ia_in_b[o];
#pragma unroll
            for (int k = 0; k < WDIM; ++k) a += cy[k] * ia_in_w[o * WDIM + k];
            ws_qkv[nc * 24 + o] = a;
        }
    }
}

// ---------------------------------------------------------------------------
// Kernel 2: global attention over 1024 tokens. 16 blocks x 64 threads,
// one query per thread; two-pass softmax (max, then exp+acc).
// ---------------------------------------------------------------------------
__global__ __launch_bounds__(64) void k_token_attn(
    const float* __restrict__ ws_cyc,
    const float* __restrict__ ws_qkv,
    const float* __restrict__ ia_out_w, const float* __restrict__ ia_out_b,
    const float* __restrict__ in_g, const float* __restrict__ in_b,
    const float* __restrict__ is_w, const float* __restrict__ is_b,
    float* __restrict__ ws_coll,  // [NCYC][8]
    float* __restrict__ ws_lg)    // [NCYC]
{
    const int g = blockIdx.x * 64 + threadIdx.x;
    float q[8];
#pragma unroll
    for (int j = 0; j < 8; ++j) q[j] = ws_qkv[g * 24 + j];

    // pass A: per-head max
    float m0 = -INFINITY, m1 = -INFINITY;
    for (int t = 0; t < NCYC; ++t) {
        const float* kr = ws_qkv + t * 24 + 8;
        float s0 = 0.f, s1 = 0.f;
#pragma unroll
        for (int d = 0; d < 4; ++d) { s0 += q[d] * kr[d]; s1 += q[4 + d] * kr[4 + d]; }
        m0 = fmaxf(m0, 0.5f * s0);
        m1 = fmaxf(m1, 0.5f * s1);
    }
    // pass B: exp + accumulate
    float l0 = 0.f, l1 = 0.f;
    float a0[4] = {0.f, 0.f, 0.f, 0.f}, a1[4] = {0.f, 0.f, 0.f, 0.f};
    for (int t = 0; t < NCYC; ++t) {
        const float* kr = ws_qkv + t * 24 + 8;
        const float* vr = ws_qkv + t * 24 + 16;
        float s0 = 0.f, s1 = 0.f;
#pragma unroll
        for (int d = 0; d < 4; ++d) { s0 += q[d] * kr[d]; s1 += q[4 + d] * kr[4 + d]; }
        const float e0 = expf(0.5f * s0 - m0);
        const float e1 = expf(0.5f * s1 - m1);
        l0 += e0; l1 += e1;
#pragma unroll
        for (int d = 0; d < 4; ++d) { a0[d] += e0 * vr[d]; a1[d] += e1 * vr[4 + d]; }
    }
    float attn8[8];
#pragma unroll
    for (int d = 0; d < 4; ++d) { attn8[d] = a0[d] / l0; attn8[4 + d] = a1[d] / l1; }

    // out proj + residual + safe + LN + safe
    float x8[8];
#pragma unroll
    for (int j = 0; j < 8; ++j) {
        float ao = ia_out_b[j];
#pragma unroll
        for (int k = 0; k < 8; ++k) ao += attn8[k] * ia_out_w[j * 8 + k];
        x8[j] = safef(ws_cyc[g * 8 + j] + ao);
    }
    float mu = 0.f;
#pragma unroll
    for (int j = 0; j < 8; ++j) mu += x8[j];
    mu *= 0.125f;
    float var = 0.f;
#pragma unroll
    for (int j = 0; j < 8; ++j) { const float d = x8[j] - mu; var += d * d; }
    var *= 0.125f;
    const float rs = rsqrtf(var + 1e-5f);
    float lgv = is_b[0];
#pragma unroll
    for (int j = 0; j < 8; ++j) {
        const float cl = safef((x8[j] - mu) * rs * in_g[j] + in_b[j]);
        ws_coll[g * 8 + j] = cl;
        lgv += cl * is_w[j];
    }
    ws_lg[g] = safef(lgv);
}

// ---------------------------------------------------------------------------
// Kernel 3: global softmax pooling over 1024 tokens + final MLP -> 8 outputs.
// ---------------------------------------------------------------------------
__global__ __launch_bounds__(NCYC) void k_final(
    const float* __restrict__ ws_coll, const float* __restrict__ ws_lg,
    const float* __restrict__ tp_ln_g, const float* __restrict__ tp_ln_b,
    const float* __restrict__ tp_w1, const float* __restrict__ tp_b1,
    const float* __restrict__ tp_w2, const float* __restrict__ tp_b2,
    float* __restrict__ out)
{
    __shared__ float scratch[NCYC][8];
    __shared__ float sred[16];
    __shared__ float sbc;
    const int tid  = threadIdx.x;
    const int lane = tid & 63;
    const int wid  = tid >> 6;

    const float lg = ws_lg[tid];
    float coll[8];
#pragma unroll
    for (int j = 0; j < 8; ++j) coll[j] = ws_coll[tid * 8 + j];

    // softmax over 1024 tokens
    float m = wmax(lg);
    if (lane == 0) sred[wid] = m;
    __syncthreads();
    if (tid == 0) {
        float M = sred[0];
        for (int i = 1; i < 16; ++i) M = fmaxf(M, sred[i]);
        sbc = M;
    }
    __syncthreads();
    const float e = expf(lg - sbc);
    float ps = wsum(e);
    __syncthreads();
    if (lane == 0) sred[wid] = ps;
    __syncthreads();
    if (tid == 0) {
        float S = 0.f;
        for (int i = 0; i < 16; ++i) S += sred[i];
        sbc = S;
    }
    __syncthreads();
    const float w = e / sbc;

#pragma unroll
    for (int j = 0; j < 8; ++j) scratch[tid][j] = w * coll[j];
    __syncthreads();
    for (int stride = 512; stride >= 1; stride >>= 1) {
        if (tid < stride) {
#pragma unroll
            for (int j = 0; j < 8; ++j) scratch[tid][j] += scratch[tid + stride][j];
        }
        __syncthreads();
    }

    if (tid == 0) {
        float p[8];
#pragma unroll
        for (int j = 0; j < 8; ++j) p[j] = scratch[0][j];
        float mu = 0.f;
#pragma unroll
        for (int j = 0; j < 8; ++j) mu += p[j];
        mu *= 0.125f;
        float var = 0.f;
#pragma unroll
        for (int j = 0; j < 8; ++j) { const float d = p[j] - mu; var += d * d; }
        var *= 0.125f;
        const float rs = rsqrtf(var + 1e-5f);
        float h[8];
#pragma unroll
        for (int j = 0; j < 8; ++j) h[j] = (p[j] - mu) * rs * tp_ln_g[j] + tp_ln_b[j];
        float r[8];
#pragma unroll
        for (int j = 0; j < 8; ++j) {
            float a = tp_b1[j];
#pragma unroll
            for (int k = 0; k < 8; ++k) a += h[k] * tp_w1[j * 8 + k];
            r[j] = fmaxf(a, 0.f);
        }
#pragma unroll
        for (int j = 0; j < 8; ++j) {
            float a = tp_b2[j];
#pragma unroll
            for (int k = 0; k < 8; ++k) a += r[k] * tp_w2[j * 8 + k];
            out[j] = safef(a);
        }
    }
}

extern "C" void kernel_launch(void* const* d_in, const int* in_sizes, int n_in,
                              void* d_out, int out_size, void* d_ws, size_t ws_size,
                              hipStream_t stream) {
    const float* df       = (const float*)d_in[0];
    const float* de_w     = (const float*)d_in[1];
    const float* de_b     = (const float*)d_in[2];
    const float* ca_in_w  = (const float*)d_in[3];
    const float* ca_in_b  = (const float*)d_in[4];
    const float* ca_out_w = (const float*)d_in[5];
    const float* ca_out_b = (const float*)d_in[6];
    const float* cn_g     = (const float*)d_in[7];
    const float* cn_b     = (const float*)d_in[8];
    const float* cs_w     = (const float*)d_in[9];
    const float* cs_b     = (const float*)d_in[10];
    const float* cp_ln_g  = (const float*)d_in[11];
    const float* cp_ln_b  = (const float*)d_in[12];
    const float* cp_w1    = (const float*)d_in[13];
    const float* cp_b1    = (const float*)d_in[14];
    const float* cp_w2    = (const float*)d_in[15];
    const float* cp_b2    = (const float*)d_in[16];
    const float* ia_in_w  = (const float*)d_in[17];
    const float* ia_in_b  = (const float*)d_in[18];
    const float* ia_out_w = (const float*)d_in[19];
    const float* ia_out_b = (const float*)d_in[20];
    const float* in_g     = (const float*)d_in[21];
    const float* in_b     = (const float*)d_in[22];
    const float* is_w     = (const float*)d_in[23];
    const float* is_b     = (const float*)d_in[24];
    const float* tp_ln_g  = (const float*)d_in[25];
    const float* tp_ln_b  = (const float*)d_in[26];
    const float* tp_w1    = (const float*)d_in[27];
    const float* tp_b1    = (const float*)d_in[28];
    const float* tp_w2    = (const float*)d_in[29];
    const float* tp_b2    = (const float*)d_in[30];

    float* ws      = (float*)d_ws;
    float* ws_cyc  = ws;                          // 1024*8
    float* ws_qkv  = ws + NCYC * 8;               // 1024*24
    float* ws_coll = ws + NCYC * (8 + 24);        // 1024*8
    float* ws_lg   = ws + NCYC * (8 + 24 + 8);    // 1024

    k_cycle<<<NCYC, LQ, 0, stream>>>(
        df, de_w, de_b, ca_in_w, ca_in_b, ca_out_w, ca_out_b,
        cn_g, cn_b, cs_w, cs_b, cp_ln_g, cp_ln_b,
        cp_w1, cp_b1, cp_w2, cp_b2, ia_in_w, ia_in_b,
        ws_cyc, ws_qkv);

    k_token_attn<<<16, 64, 0, stream>>>(
        ws_cyc, ws_qkv, ia_out_w, ia_out_b, in_g, in_b, is_w, is_b,
        ws_coll, ws_lg);

    k_final<<<1, NCYC, 0, stream>>>(
        ws_coll, ws_lg, tp_ln_g, tp_ln_b, tp_w1, tp_b1, tp_w2, tp_b2,
        (float*)d_out);
}

// Round 2
// 135.655 us; speedup vs baseline: 2.7947x; 2.7947x over previous
//
#include <hip/hip_runtime.h>
#include <math.h>

#define FCLAMP 10000.0f
#define LQ 256
#define NCYC 1024
#define WDIM 8

__device__ __forceinline__ float safef(float x) {
    if (isnan(x)) return 0.0f;
    x = fminf(x, FCLAMP);
    x = fmaxf(x, -FCLAMP);
    return x;
}

// Butterfly reductions: every lane ends with the full-wave result.
__device__ __forceinline__ float wsum_b(float v) {
#pragma unroll
    for (int m = 1; m <= 32; m <<= 1) v += __shfl_xor(v, m, 64);
    return v;
}
__device__ __forceinline__ float wmax_b(float v) {
#pragma unroll
    for (int m = 1; m <= 32; m <<= 1) v = fmaxf(v, __shfl_xor(v, m, 64));
    return v;
}

// ---------------------------------------------------------------------------
// Kernel 1: one block per cycle (256 threads, one per dart).
// Orientation normalization (wave shuffle scan), dart embed, 3-neighbor cycle
// attention, residual+LN, softmax pooling, per-cycle MLP -> cycle token, and
// the global-attention QKV row (transposed K/V layout for kernel 2).
// ---------------------------------------------------------------------------
__global__ __launch_bounds__(LQ) void k_cycle(
    const float* __restrict__ df,
    const float* __restrict__ de_w, const float* __restrict__ de_b,
    const float* __restrict__ ca_in_w, const float* __restrict__ ca_in_b,
    const float* __restrict__ ca_out_w, const float* __restrict__ ca_out_b,
    const float* __restrict__ cn_g, const float* __restrict__ cn_b,
    const float* __restrict__ cs_w, const float* __restrict__ cs_b,
    const float* __restrict__ cp_ln_g, const float* __restrict__ cp_ln_b,
    const float* __restrict__ cp_w1, const float* __restrict__ cp_b1,
    const float* __restrict__ cp_w2, const float* __restrict__ cp_b2,
    const float* __restrict__ ia_in_w, const float* __restrict__ ia_in_b,
    float* __restrict__ ws_cyc,   // [NCYC][8]
    float* __restrict__ ws_q,     // [NCYC][8]
    float* __restrict__ ws_kT,    // [8][NCYC]
    float* __restrict__ ws_vT)    // [8][NCYC]
{
    __shared__ float sdx[LQ], sdy[LQ];
    __shared__ float sk[LQ][9], sv[LQ][9];   // pad 9: kill 8-way bank conflicts
    __shared__ float swx[4], swy[4];
    __shared__ float sredA[4], sredB[4];
    __shared__ float spool[4][WDIM];

    const int tid  = threadIdx.x;
    const int nc   = blockIdx.x;
    const int lane = tid & 63;
    const int wid  = tid >> 6;

    const float* base = df + (size_t)nc * (LQ * 3);
    const float dx = base[tid * 3 + 0];
    const float dy = base[tid * 3 + 1];
    sdx[tid] = dx; sdy[tid] = dy;

    // In-wave inclusive scan via shuffles (no LDS, no barriers).
    float ix = dx, iy = dy;
#pragma unroll
    for (int off = 1; off < 64; off <<= 1) {
        const float tx = __shfl_up(ix, off, 64);
        const float ty = __shfl_up(iy, off, 64);
        if (lane >= off) { ix += tx; iy += ty; }
    }
    if (lane == 63) { swx[wid] = ix; swy[wid] = iy; }
    __syncthreads();
    float ox = 0.f, oy = 0.f;
    for (int w = 0; w < wid; ++w) { ox += swx[w]; oy += swy[w]; }
    // exclusive prefix = vertex position
    const float vx = ox + ix - dx;
    const float vy = oy + iy - dy;
    // shoelace: area*2 = sum_{i<L-1} cross(v_i, d_i)
    float c = (tid < LQ - 1) ? (vx * dy - vy * dx) : 0.f;
    float s = wsum_b(c);
    if (lane == 0) sredA[wid] = s;
    __syncthreads();
    const float area2 = sredA[0] + sredA[1] + sredA[2] + sredA[3];
    const bool flip = !(area2 >= 0.f);

    float xx, yy;
    if (flip) { xx = -sdx[LQ - 1 - tid]; yy = -sdy[LQ - 1 - tid]; }
    else      { xx =  dx;                yy =  dy; }

    const float fx = safef(xx);
    const float fy = safef(yy);
    const float fn = safef(sqrtf(xx * xx + yy * yy));

    float emb[WDIM];
#pragma unroll
    for (int j = 0; j < WDIM; ++j) {
        float e = de_b[j] + fx * de_w[j * 3 + 0] + fy * de_w[j * 3 + 1] + fn * de_w[j * 3 + 2];
        emb[j] = safef(fmaxf(e, 0.f));
    }

    // qkv = emb @ ca_in_w.T + b ; q,k,v of self in regs; k,v also to LDS
    float q[WDIM], kk[WDIM], vv[WDIM];
#pragma unroll
    for (int o = 0; o < 24; ++o) {
        float val = ca_in_b[o];
#pragma unroll
        for (int k = 0; k < WDIM; ++k) val += emb[k] * ca_in_w[o * WDIM + k];
        if (o < 8)       q[o] = val;
        else if (o < 16) { kk[o - 8]  = val; sk[tid][o - 8]  = val; }
        else             { vv[o - 16] = val; sv[tid][o - 16] = val; }
    }
    __syncthreads();

    // Cycle attention: mask allows {i-1, i, i+1} circular; exact 3-way softmax.
    const int ip  = (tid + LQ - 1) & (LQ - 1);
    const int inx = (tid + 1) & (LQ - 1);
    float attn8[WDIM];
#pragma unroll
    for (int h = 0; h < 2; ++h) {
        float s0 = 0.f, s1 = 0.f, s2 = 0.f;
#pragma unroll
        for (int d = 0; d < 4; ++d) {
            const float qv = q[h * 4 + d];
            s0 += qv * sk[ip][h * 4 + d];
            s1 += qv * kk[h * 4 + d];
            s2 += qv * sk[inx][h * 4 + d];
        }
        s0 *= 0.5f; s1 *= 0.5f; s2 *= 0.5f;
        const float m  = fmaxf(s0, fmaxf(s1, s2));
        const float e0 = __expf(s0 - m), e1 = __expf(s1 - m), e2 = __expf(s2 - m);
        const float inv = 1.f / (e0 + e1 + e2);
#pragma unroll
        for (int d = 0; d < 4; ++d)
            attn8[h * 4 + d] = (e0 * sv[ip][h * 4 + d] + e1 * vv[h * 4 + d] +
                                e2 * sv[inx][h * 4 + d]) * inv;
    }

    // out proj + residual + safe + LN + safe
    float x8[WDIM];
#pragma unroll
    for (int j = 0; j < WDIM; ++j) {
        float ao = ca_out_b[j];
#pragma unroll
        for (int k = 0; k < WDIM; ++k) ao += attn8[k] * ca_out_w[j * WDIM + k];
        x8[j] = safef(emb[j] + ao);
    }
    float mu = 0.f;
#pragma unroll
    for (int j = 0; j < WDIM; ++j) mu += x8[j];
    mu *= (1.f / WDIM);
    float var = 0.f;
#pragma unroll
    for (int j = 0; j < WDIM; ++j) { const float d = x8[j] - mu; var += d * d; }
    var *= (1.f / WDIM);
    const float rs = rsqrtf(var + 1e-5f);
    float emb2[WDIM];
#pragma unroll
    for (int j = 0; j < WDIM; ++j)
        emb2[j] = safef((x8[j] - mu) * rs * cn_g[j] + cn_b[j]);

    // dart logit + block softmax
    float lg = cs_b[0];
#pragma unroll
    for (int j = 0; j < WDIM; ++j) lg += emb2[j] * cs_w[j];
    lg = safef(lg);

    float wm = wmax_b(lg);
    if (lane == 0) sredB[wid] = wm;
    __syncthreads();
    const float M = fmaxf(fmaxf(sredB[0], sredB[1]), fmaxf(sredB[2], sredB[3]));
    const float e = __expf(lg - M);
    float psum = wsum_b(e);
    if (lane == 0) sredA[wid] = psum;
    __syncthreads();
    const float S = sredA[0] + sredA[1] + sredA[2] + sredA[3];
    const float wgt = e / S;

    // pooled[j] = sum_i wgt_i * emb2_i[j]   (wave butterfly, cross-wave LDS)
#pragma unroll
    for (int j = 0; j < WDIM; ++j) {
        const float pj = wsum_b(wgt * emb2[j]);
        if (lane == 0) spool[wid][j] = pj;
    }
    __syncthreads();

    if (wid == 0) {
        const int l8 = lane & 7;
        const float p = spool[0][l8] + spool[1][l8] + spool[2][l8] + spool[3][l8];
        // LN over the 8 lanes of group 0 (lanes>=8 compute garbage, unused)
        float mu2 = p;
        mu2 += __shfl_xor(mu2, 1, 8); mu2 += __shfl_xor(mu2, 2, 8); mu2 += __shfl_xor(mu2, 4, 8);
        mu2 *= 0.125f;
        const float dd = p - mu2;
        float v2 = dd * dd;
        v2 += __shfl_xor(v2, 1, 8); v2 += __shfl_xor(v2, 2, 8); v2 += __shfl_xor(v2, 4, 8);
        const float rs2 = rsqrtf(v2 * 0.125f + 1e-5f);
        const float hh = dd * rs2 * cp_ln_g[l8] + cp_ln_b[l8];
        // r_j = relu(hh @ w1.T + b1)
        float a = cp_b1[l8];
#pragma unroll
        for (int k = 0; k < 8; ++k) a += __shfl(hh, k, 8) * cp_w1[l8 * 8 + k];
        const float r = fmaxf(a, 0.f);
        a = cp_b2[l8];
#pragma unroll
        for (int k = 0; k < 8; ++k) a += __shfl(r, k, 8) * cp_w2[l8 * 8 + k];
        const float cy = safef(a);
        if (lane < 8) ws_cyc[nc * 8 + lane] = cy;
        // global-attention qkv row: lanes 0..23 compute one output each
        const int o = (lane < 24) ? lane : 0;
        float g2 = ia_in_b[o];
#pragma unroll
        for (int k = 0; k < 8; ++k) g2 += __shfl(cy, k, 64) * ia_in_w[o * 8 + k];
        if (lane < 8)       ws_q[nc * 8 + lane] = g2;
        else if (lane < 16) ws_kT[(lane - 8) * NCYC + nc] = g2;
        else if (lane < 24) ws_vT[(lane - 16) * NCYC + nc] = g2;
    }
}

// ---------------------------------------------------------------------------
// Kernel 2: global attention over 1024 tokens. One WAVE per query: lanes
// split the keys (16 each), scores live in registers, butterfly reductions.
// 256 blocks x 256 threads (4 queries/block). No barriers, no LDS.
// ---------------------------------------------------------------------------
__global__ __launch_bounds__(256) void k_token_attn(
    const float* __restrict__ ws_cyc,
    const float* __restrict__ ws_q,
    const float* __restrict__ ws_kT,
    const float* __restrict__ ws_vT,
    const float* __restrict__ ia_out_w, const float* __restrict__ ia_out_b,
    const float* __restrict__ in_g, const float* __restrict__ in_b,
    const float* __restrict__ is_w, const float* __restrict__ is_b,
    float* __restrict__ ws_coll,  // [NCYC][8]
    float* __restrict__ ws_lg)    // [NCYC]
{
    const int lane = threadIdx.x & 63;
    const int wid  = threadIdx.x >> 6;
    const int g    = blockIdx.x * 4 + wid;

    float q[8];
#pragma unroll
    for (int d = 0; d < 8; ++d) q[d] = ws_q[g * 8 + d];

    // pass A: scores into registers, track per-lane max
    float sc0[16], sc1[16];
    float m0 = -1e30f, m1 = -1e30f;
#pragma unroll
    for (int j = 0; j < 16; ++j) {
        const int t = (j << 6) | lane;
        float s0 = 0.f, s1 = 0.f;
#pragma unroll
        for (int d = 0; d < 4; ++d) {
            s0 += q[d]     * ws_kT[d * NCYC + t];
            s1 += q[4 + d] * ws_kT[(4 + d) * NCYC + t];
        }
        sc0[j] = s0; sc1[j] = s1;
        m0 = fmaxf(m0, s0); m1 = fmaxf(m1, s1);
    }
    m0 = wmax_b(m0); m1 = wmax_b(m1);

    // pass B: exp + accumulate (scores from regs, V coalesced)
    float l0 = 0.f, l1 = 0.f;
    float a0[4] = {0.f, 0.f, 0.f, 0.f}, a1[4] = {0.f, 0.f, 0.f, 0.f};
#pragma unroll
    for (int j = 0; j < 16; ++j) {
        const int t = (j << 6) | lane;
        const float e0 = __expf(0.5f * (sc0[j] - m0));
        const float e1 = __expf(0.5f * (sc1[j] - m1));
        l0 += e0; l1 += e1;
#pragma unroll
        for (int d = 0; d < 4; ++d) {
            a0[d] += e0 * ws_vT[d * NCYC + t];
            a1[d] += e1 * ws_vT[(4 + d) * NCYC + t];
        }
    }
    l0 = wsum_b(l0); l1 = wsum_b(l1);
#pragma unroll
    for (int d = 0; d < 4; ++d) { a0[d] = wsum_b(a0[d]); a1[d] = wsum_b(a1[d]); }

    float attn8[8];
#pragma unroll
    for (int d = 0; d < 4; ++d) { attn8[d] = a0[d] / l0; attn8[4 + d] = a1[d] / l1; }

    // epilogue (all lanes redundantly; lane 0 stores)
    float x8[8];
#pragma unroll
    for (int j = 0; j < 8; ++j) {
        float ao = ia_out_b[j];
#pragma unroll
        for (int k = 0; k < 8; ++k) ao += attn8[k] * ia_out_w[j * 8 + k];
        x8[j] = safef(ws_cyc[g * 8 + j] + ao);
    }
    float mu = 0.f;
#pragma unroll
    for (int j = 0; j < 8; ++j) mu += x8[j];
    mu *= 0.125f;
    float var = 0.f;
#pragma unroll
    for (int j = 0; j < 8; ++j) { const float d = x8[j] - mu; var += d * d; }
    var *= 0.125f;
    const float rs = rsqrtf(var + 1e-5f);
    float lgv = is_b[0];
    float cl8[8];
#pragma unroll
    for (int j = 0; j < 8; ++j) {
        cl8[j] = safef((x8[j] - mu) * rs * in_g[j] + in_b[j]);
        lgv += cl8[j] * is_w[j];
    }
    if (lane == 0) {
#pragma unroll
        for (int j = 0; j < 8; ++j) ws_coll[g * 8 + j] = cl8[j];
        ws_lg[g] = safef(lgv);
    }
}

// ---------------------------------------------------------------------------
// Kernel 3: global softmax pooling over 1024 tokens + final MLP -> 8 outputs.
// ---------------------------------------------------------------------------
__global__ __launch_bounds__(NCYC) void k_final(
    const float* __restrict__ ws_coll, const float* __restrict__ ws_lg,
    const float* __restrict__ tp_ln_g, const float* __restrict__ tp_ln_b,
    const float* __restrict__ tp_w1, const float* __restrict__ tp_b1,
    const float* __restrict__ tp_w2, const float* __restrict__ tp_b2,
    float* __restrict__ out)
{
    __shared__ float sredA[16], sredB[16];
    __shared__ float spool[16][8];
    const int tid  = threadIdx.x;
    const int lane = tid & 63;
    const int wid  = tid >> 6;

    const float lg = ws_lg[tid];
    float coll[8];
#pragma unroll
    for (int j = 0; j < 8; ++j) coll[j] = ws_coll[tid * 8 + j];

    float wm = wmax_b(lg);
    if (lane == 0) sredA[wid] = wm;
    __syncthreads();
    float M = sredA[0];
    for (int i = 1; i < 16; ++i) M = fmaxf(M, sredA[i]);
    const float e = __expf(lg - M);
    float ps = wsum_b(e);
    if (lane == 0) sredB[wid] = ps;
    __syncthreads();
    float S = 0.f;
    for (int i = 0; i < 16; ++i) S += sredB[i];
    const float w = e / S;

#pragma unroll
    for (int j = 0; j < 8; ++j) {
        const float pj = wsum_b(w * coll[j]);
        if (lane == 0) spool[wid][j] = pj;
    }
    __syncthreads();

    if (wid == 0) {
        const int l8 = lane & 7;
        float p = 0.f;
        for (int i = 0; i < 16; ++i) p += spool[i][l8];
        float mu = p;
        mu += __shfl_xor(mu, 1, 8); mu += __shfl_xor(mu, 2, 8); mu += __shfl_xor(mu, 4, 8);
        mu *= 0.125f;
        const float dd = p - mu;
        float v2 = dd * dd;
        v2 += __shfl_xor(v2, 1, 8); v2 += __shfl_xor(v2, 2, 8); v2 += __shfl_xor(v2, 4, 8);
        const float rs = rsqrtf(v2 * 0.125f + 1e-5f);
        const float h = dd * rs * tp_ln_g[l8] + tp_ln_b[l8];
        float a = tp_b1[l8];
#pragma unroll
        for (int k = 0; k < 8; ++k) a += __shfl(h, k, 8) * tp_w1[l8 * 8 + k];
        const float r = fmaxf(a, 0.f);
        a = tp_b2[l8];
#pragma unroll
        for (int k = 0; k < 8; ++k) a += __shfl(r, k, 8) * tp_w2[l8 * 8 + k];
        if (lane < 8) out[lane] = safef(a);
    }
}

extern "C" void kernel_launch(void* const* d_in, const int* in_sizes, int n_in,
                              void* d_out, int out_size, void* d_ws, size_t ws_size,
                              hipStream_t stream) {
    const float* df       = (const float*)d_in[0];
    const float* de_w     = (const float*)d_in[1];
    const float* de_b     = (const float*)d_in[2];
    const float* ca_in_w  = (const float*)d_in[3];
    const float* ca_in_b  = (const float*)d_in[4];
    const float* ca_out_w = (const float*)d_in[5];
    const float* ca_out_b = (const float*)d_in[6];
    const float* cn_g     = (const float*)d_in[7];
    const float* cn_b     = (const float*)d_in[8];
    const float* cs_w     = (const float*)d_in[9];
    const float* cs_b     = (const float*)d_in[10];
    const float* cp_ln_g  = (const float*)d_in[11];
    const float* cp_ln_b  = (const float*)d_in[12];
    const float* cp_w1    = (const float*)d_in[13];
    const float* cp_b1    = (const float*)d_in[14];
    const float* cp_w2    = (const float*)d_in[15];
    const float* cp_b2    = (const float*)d_in[16];
    const float* ia_in_w  = (const float*)d_in[17];
    const float* ia_in_b  = (const float*)d_in[18];
    const float* ia_out_w = (const float*)d_in[19];
    const float* ia_out_b = (const float*)d_in[20];
    const float* in_g     = (const float*)d_in[21];
    const float* in_b     = (const float*)d_in[22];
    const float* is_w     = (const float*)d_in[23];
    const float* is_b     = (const float*)d_in[24];
    const float* tp_ln_g  = (const float*)d_in[25];
    const float* tp_ln_b  = (const float*)d_in[26];
    const float* tp_w1    = (const float*)d_in[27];
    const float* tp_b1    = (const float*)d_in[28];
    const float* tp_w2    = (const float*)d_in[29];
    const float* tp_b2    = (const float*)d_in[30];

    float* ws      = (float*)d_ws;
    float* ws_cyc  = ws;                    // 1024*8
    float* ws_q    = ws + NCYC * 8;         // 1024*8
    float* ws_kT   = ws + NCYC * 16;        // 8*1024 (transposed)
    float* ws_vT   = ws + NCYC * 24;        // 8*1024 (transposed)
    float* ws_coll = ws + NCYC * 32;        // 1024*8
    float* ws_lg   = ws + NCYC * 40;        // 1024

    k_cycle<<<NCYC, LQ, 0, stream>>>(
        df, de_w, de_b, ca_in_w, ca_in_b, ca_out_w, ca_out_b,
        cn_g, cn_b, cs_w, cs_b, cp_ln_g, cp_ln_b,
        cp_w1, cp_b1, cp_w2, cp_b2, ia_in_w, ia_in_b,
        ws_cyc, ws_q, ws_kT, ws_vT);

    k_token_attn<<<NCYC / 4, 256, 0, stream>>>(
        ws_cyc, ws_q, ws_kT, ws_vT, ia_out_w, ia_out_b, in_g, in_b, is_w, is_b,
        ws_coll, ws_lg);

    k_final<<<1, NCYC, 0, stream>>>(
        ws_coll, ws_lg, tp_ln_g, tp_ln_b, tp_w1, tp_b1, tp_w2, tp_b2,
        (float*)d_out);
}